// Round 8
// baseline (249.565 us; speedup 1.0000x reference)
//
#include <hip/hip_runtime.h>
#include <hip/hip_fp16.h>

#define IN_C 64
#define HID_C 64
#define OUT_C 32
#define S_NODES  512    // bucket width in nodes
#define S_CAP  12288    // staging capacity per bucket (mean 8192, sigma ~90)
#define CHUNK_E 4096    // edges per bin block (16 per thread, register-cached)
// Packing invariant: src fits in 17 bits (N <= 131072), dst-local in 9 bits.

typedef _Float16 f16_t;
typedef f16_t f16x2 __attribute__((ext_vector_type(2)));

// 2 f16 MACs, fp32 accumulate (v_dot2_f32_f16). Both operands as packed u32.
__device__ __forceinline__ float dot2(unsigned int a, unsigned int b, float c) {
#if __has_builtin(__builtin_amdgcn_fdot2)
    return __builtin_amdgcn_fdot2(*(f16x2*)&a, *(f16x2*)&b, c, false);
#else
    float2 af = __half22float2(*(__half2*)&a);
    float2 bf = __half22float2(*(__half2*)&b);
    return fmaf(af.x, bf.x, fmaf(af.y, bf.y, c));
#endif
}

// s0 += f16lo(p)*w ; s1 += f16hi(p)*w  -- v_fma_mix_f32 does the f16->f32
// convert inside the FMA (bit-exact with cvt+fmaf, half the instructions).
__device__ __forceinline__ void mix2(float& s0, float& s1, unsigned int p, float w) {
    asm("v_fma_mix_f32 %0, %2, %3, %0 op_sel:[0,0,0] op_sel_hi:[1,0,0]\n\t"
        "v_fma_mix_f32 %1, %2, %3, %1 op_sel:[1,0,0] op_sel_hi:[1,0,0]"
        : "+v"(s0), "+v"(s1)
        : "v"(p), "v"(w));
}

// Wave-level inclusive scan (64 lanes) via shfl_up; 6 steps, no barriers.
__device__ __forceinline__ int wave_iscan(int x, int lane) {
#pragma unroll
    for (int o = 1; o < 64; o <<= 1) {
        int y = __shfl_up(x, o);
        if (lane >= o) x += y;
    }
    return x;
}

// ---------------------------------------------------------------------------
// fat: three independent jobs in one launch (overlap without streams, which
// graph capture forbids):
//   blocks [0, NEB)        : bin_edges -- single-pass edge read into VGPR
//                            cache (16 records/thread, dword loads only),
//                            LDS histogram + wave-shfl scan, LDS counting-
//                            sort, burst-copy segments into bucket staging.
//                            is64 detected inline per block.
//   blocks [NEB, NEB+GB)   : gemm1: t32[r,:] = x[r,:] @ W1 in FP32, UNSCALED
//                            (64 rows/block; dinv doesn't exist yet --
//                            place_fine applies it in its coalesced convert).
//   block  NEB+GB          : W2/Wlin -> f16 col-major for later kernels.
// ---------------------------------------------------------------------------
__global__ __launch_bounds__(256) void fat(const void* ei, int E,
                                           int* bcur, int NB,
                                           int* __restrict__ staging,
                                           int NEB, int GB,
                                           const float* __restrict__ x,
                                           const float* __restrict__ W1,
                                           float* __restrict__ t32, int n,
                                           const float* __restrict__ W2,
                                           const float* __restrict__ Wlin,
                                           unsigned short* __restrict__ Wh2,
                                           unsigned short* __restrict__ Whl) {
    // union: bin = cnt(256)+boff(256)+lcur(256)+gbase(256)+stg(4096)+misc
    //        gemm = sA (8 KB = 2048 ints)
    __shared__ __align__(16) int smem[5128];
    int tid = threadIdx.x;
    int b = blockIdx.x;
    if (b < NEB) {
        // ----- bin_edges -----
        int* cnt = smem;          int* boff = smem + 256;
        int* lcur = smem + 512;   int* gbase = smem + 768;
        int* stg = smem + 1024;   // CHUNK_E ints
        int* ps64 = smem + 5120;
        int* wsum = smem + 5121;  // 4 wave partial sums
        int lane = tid & 63, wv = tid >> 6;
        if (tid == 0) *ps64 = 1;
        cnt[tid] = 0;
        __syncthreads();
        // int32 interp: odd ints are real node ids (nonzero w.h.p.);
        // int64 interp: odd ints are high dwords (always 0 for ids < 2^31).
        if (2 * tid + 1 < 2 * E && ((const int*)ei)[2 * tid + 1] != 0) *ps64 = 0;
        __syncthreads();
        int is64 = *ps64;
        int e0 = b * CHUNK_E;
        int e1 = min(E, e0 + CHUNK_E);
        const int* ei32 = (const int*)ei;
        int rbuf[16];   // packed record  src | ((dst&511)<<17)
        int bbuf[16];   // bucket id (dst>>9), -1 = invalid slot
        if (is64) {
#pragma unroll
            for (int k = 0; k < 16; k++) {
                int e = e0 + (k << 8) + tid;
                if (e < e1) {
                    int src = ei32[2 * e];            // low dword of int64
                    int dst = ei32[2 * (E + e)];
                    rbuf[k] = src | ((dst & 511) << 17);
                    int bk = dst >> 9;
                    bbuf[k] = bk;
                    atomicAdd(&cnt[bk], 1);
                } else bbuf[k] = -1;
            }
        } else {
#pragma unroll
            for (int k = 0; k < 16; k++) {
                int e = e0 + (k << 8) + tid;
                if (e < e1) {
                    int src = ei32[e];
                    int dst = ei32[E + e];
                    rbuf[k] = src | ((dst & 511) << 17);
                    int bk = dst >> 9;
                    bbuf[k] = bk;
                    atomicAdd(&cnt[bk], 1);
                } else bbuf[k] = -1;
            }
        }
        __syncthreads();
        // exclusive scan of cnt via wave-shfl (2 barriers)
        int v = cnt[tid];
        int xx = wave_iscan(v, lane);
        if (lane == 63) wsum[wv] = xx;
        __syncthreads();
        int add = 0;
#pragma unroll
        for (int w = 0; w < 3; w++) add += (w < wv) ? wsum[w] : 0;
        int bo = xx + add - v;
        boff[tid] = bo;
        lcur[tid] = bo;
        __syncthreads();
        // counting-sort scatter from registers
#pragma unroll
        for (int k = 0; k < 16; k++) {
            if (bbuf[k] >= 0) {
                int p = atomicAdd(&lcur[bbuf[k]], 1);
                stg[p] = rbuf[k];
            }
        }
        __syncthreads();
        if (tid < NB && cnt[tid] > 0) gbase[tid] = atomicAdd(&bcur[tid], cnt[tid]);
        __syncthreads();
        int sw = tid >> 4, sl = tid & 15;  // 16 subwaves of 16 lanes
        for (int bk = sw; bk < NB; bk += 16) {
            int c = cnt[bk];
            if (c == 0) continue;
            int o = boff[bk], g = gbase[bk];
            size_t gb = (size_t)bk * S_CAP;
            for (int j = sl; j < c; j += 16) {
                if (g + j < S_CAP) staging[gb + g + j] = stg[o + j];  // clamp (never hits)
            }
        }
    } else if (b < NEB + GB) {
        // ----- gemm1: fp32 unscaled x @ W1, 64 rows/block -----
        uint4* sA = (uint4*)smem;  // 64 rows x 64 f16 = 8 KB
        int bb = b - NEB;
        int lane = tid & 63, wave = tid >> 6;
        unsigned int wu[32];
#pragma unroll
        for (int k = 0; k < 32; k++) {
            f16x2 p;
            p.x = (f16_t)W1[(2 * k) * 64 + lane];
            p.y = (f16_t)W1[(2 * k + 1) * 64 + lane];
            wu[k] = *(unsigned int*)&p;
        }
        int base = bb * 64;
        const float2* A2 = (const float2*)x;
        int lim = n * 32;
        for (int i = tid; i < 2048; i += 256) {
            int gi = base * 32 + i;
            float2 v = (gi < lim) ? A2[gi] : make_float2(0.f, 0.f);
            ((__half2*)sA)[i] = __floats2half2_rn(v.x, v.y);
        }
        __syncthreads();
        int r0 = base + wave * 16;
        int r1 = min(r0 + 16, n);
        for (int r = r0; r < r1; r++) {
            int rr = r - base;
            float a0 = 0.f, a1 = 0.f;
#pragma unroll
            for (int j = 0; j < 8; j++) {
                uint4 u = sA[rr * 8 + j];  // uniform addr -> LDS broadcast, b128
                a0 = dot2(u.x, wu[4 * j], a0);
                a1 = dot2(u.y, wu[4 * j + 1], a1);
                a0 = dot2(u.z, wu[4 * j + 2], a0);
                a1 = dot2(u.w, wu[4 * j + 3], a1);
            }
            t32[(size_t)r * 64 + lane] = a0 + a1;
        }
    } else {
        // ----- W2 / Wlin -> f16 col-major -----
        for (int i = tid; i < 4096; i += 256) {
            int r = i >> 6, c = i & 63;
            f16_t h2 = (f16_t)W2[r * 64 + c];
            Wh2[c * 64 + r] = *(unsigned short*)&h2;
        }
        for (int i = tid; i < 2048; i += 256) {
            int r = i >> 5, c = i & 31;
            f16_t h = (f16_t)Wlin[r * 32 + c];
            Whl[c * 64 + r] = *(unsigned short*)&h;
        }
    }
}

// ---------------------------------------------------------------------------
// Pass B: one block per bucket, 1024 threads. Wave-shfl scans; LDS degree
// histogram of the staged records -> offs/dinv/cursors; scatter of src
// records into the bucket's contiguous rec region; then the coalesced
// scale+convert pass t16[r,:] = f16(t32[r,:]*dinv[r]).
// ---------------------------------------------------------------------------
__global__ __launch_bounds__(1024) void place_fine(const int* __restrict__ staging,
                                                   const int* __restrict__ bcur,
                                                   int* __restrict__ offs,
                                                   float* __restrict__ dinv,
                                                   int* __restrict__ rec,
                                                   const float* __restrict__ t32,
                                                   unsigned short* __restrict__ t16,
                                                   int N, int NB) {
    __shared__ int sdeg[S_NODES];
    __shared__ int curs[S_NODES];
    __shared__ int sb[256];
    __shared__ float sdinv[S_NODES];
    __shared__ int wsum[16];
    int tid = threadIdx.x;
    int lane = tid & 63, wv = tid >> 6;
    if (tid < S_NODES) sdeg[tid] = 0;
    // scan A (first 4 waves): bucket counts -> sb (inclusive)
    if (tid < 256) {
        int v = (tid < NB) ? min(bcur[tid], S_CAP) : 0;
        int xx = wave_iscan(v, lane);
        if (lane == 63) wsum[wv] = xx;
        sb[tid] = xx;  // partial; fixed after barrier
    }
    __syncthreads();
    if (tid < 256) {
        int add = 0;
#pragma unroll
        for (int w = 0; w < 3; w++) add += (w < wv) ? wsum[w] : 0;
        sb[tid] += add;
    }
    __syncthreads();
    int cnt = min(bcur[blockIdx.x], S_CAP);
    int bbase = sb[blockIdx.x] - cnt;  // exclusive prefix for this bucket
    if (blockIdx.x == NB - 1 && tid == 0) offs[N] = sb[255];
    int base = blockIdx.x * S_NODES;
    int nn = min(S_NODES, N - base);
    size_t sbase = (size_t)blockIdx.x * S_CAP;
    for (int j = tid; j < cnt; j += 1024) atomicAdd(&sdeg[staging[sbase + j] >> 17], 1);
    __syncthreads();
    // scan B (first 8 waves, 1 degree/thread): degrees -> exclusive prefix
    int d = (tid < S_NODES) ? sdeg[tid] : 0;
    int x2 = wave_iscan(d, lane);
    if (tid < S_NODES && lane == 63) wsum[wv] = x2;
    __syncthreads();
    if (tid < S_NODES) {
        int add2 = 0;
#pragma unroll
        for (int w = 0; w < 7; w++) add2 += (w < wv) ? wsum[w] : 0;
        int pre = bbase + x2 + add2 - d;  // exclusive
        curs[tid] = pre;
        float dv = rsqrtf((float)(d + 1));
        sdinv[tid] = dv;
        if (tid < nn) {
            offs[base + tid] = pre;
            dinv[base + tid] = dv;
        }
    }
    __syncthreads();
    for (int j = tid; j < cnt; j += 1024) {
        int pk = staging[sbase + j];
        int p = atomicAdd(&curs[pk >> 17], 1);
        rec[p] = pk & 0x1FFFF;
    }
    // ----- scale+convert this bucket's rows: t16[r,:] = f16(t32[r,:]*dinv[r])
    const float4* tin = (const float4*)t32 + (size_t)base * 16;  // 16 float4/row
    uint2* tout = (uint2*)t16 + (size_t)base * 16;               // 16 uint2/row
    int jmax = nn * 16;
    for (int j = tid; j < jmax; j += 1024) {
        float4 vv = tin[j];
        float w = sdinv[j >> 4];
        __half2 h0 = __floats2half2_rn(vv.x * w, vv.y * w);
        __half2 h1 = __floats2half2_rn(vv.z * w, vv.w * w);
        tout[j] = make_uint2(*(unsigned int*)&h0, *(unsigned int*)&h1);
    }
}

// ---------------------------------------------------------------------------
// aggregate helpers. EDGE-ONLY chunks (the self row is handled outside the
// loop): interior chunks (MASK=false, 32 edges guaranteed) carry zero
// select/mask code -- pure batched loads + mix-fma with w=1. Tail chunks
// lose the old it==0 special-case and index bias. NU selected by wave-
// uniform remainder -> pure s_cbranch, no divergence; loads stay batched
// (round-2 lesson).
// ---------------------------------------------------------------------------
__device__ __forceinline__ void agg_consume(const uint4& v, float w, float s[8]) {
    mix2(s[0], s[1], v.x, w);
    mix2(s[2], s[3], v.y, w);
    mix2(s[4], s[5], v.z, w);
    mix2(s[6], s[7], v.w, w);
}

template <int NU, bool MASK>
__device__ __forceinline__ void agg_chunk(const uint4* __restrict__ t4,
                                          const int* __restrict__ rec,
                                          int beg, int node, int me, int i,
                                          int g, int gl, float s[8]) {
    int srcs[NU];
    float ws[NU];
    uint4 vs[NU];
#pragma unroll
    for (int u = 0; u < NU; u++) {
        int it = i + u * 8 + g;
        if (MASK) {
            // OOB rec reads (it>=me) land in the staging region that follows
            // rec in the workspace; value is masked by ws=0.
            srcs[u] = (it < me) ? rec[beg + it] : node;
            ws[u] = (it < me) ? 1.f : 0.f;
        } else {
            srcs[u] = rec[beg + it];
        }
    }
#pragma unroll
    for (int u = 0; u < NU; u++) vs[u] = t4[(size_t)srcs[u] * 8 + gl];
#pragma unroll
    for (int u = 0; u < NU; u++) agg_consume(vs[u], MASK ? ws[u] : 1.f, s);
}

// ---------------------------------------------------------------------------
// acc[n,:] = f16( relu( b + dinv[n] * ( t[n,:] + sum_{edges->n} t[src,:] )))
// t rows pre-scaled by dinv[src]. One wave per node: 8 groups x 8 lanes;
// each group fetches one edge's 128B row as uint4. The SELF row is loaded
// once (predicated, issued before the gather loop to hide latency) and
// added by the g==0 lanes after the shuffle-reduce. Isolated nodes skip
// the gather loop entirely. fp32 accum.
// ---------------------------------------------------------------------------
__global__ void aggregate(const unsigned short* __restrict__ t,
                          const int* __restrict__ offs, const int* __restrict__ rec,
                          const float* __restrict__ dinv, const float* __restrict__ bias,
                          unsigned short* __restrict__ acc, int n) {
    int wave = (blockIdx.x * blockDim.x + threadIdx.x) >> 6;
    int lane = threadIdx.x & 63;
    if (wave >= n) return;
    int g = lane >> 3;   // edge group 0..7
    int gl = lane & 7;   // 16B slot within the 128B row
    int beg = offs[wave], end = offs[wave + 1];
    int me = end - beg;  // edge count (self handled separately)
    const uint4* t4 = (const uint4*)t;
    uint4 selfv;
    if (g == 0) selfv = t4[(size_t)wave * 8 + gl];  // exec-masked early load
    float s[8] = {0.f, 0.f, 0.f, 0.f, 0.f, 0.f, 0.f, 0.f};
    int i = 0;
    for (; me - i >= 32; i += 32) agg_chunk<4, false>(t4, rec, beg, wave, me, i, g, gl, s);
    int rem = me - i;  // wave-uniform, 0..31
    if (rem > 24)      agg_chunk<4, true>(t4, rec, beg, wave, me, i, g, gl, s);
    else if (rem > 16) agg_chunk<3, true>(t4, rec, beg, wave, me, i, g, gl, s);
    else if (rem > 8)  agg_chunk<2, true>(t4, rec, beg, wave, me, i, g, gl, s);
    else if (rem > 0)  agg_chunk<1, true>(t4, rec, beg, wave, me, i, g, gl, s);
#pragma unroll
    for (int k = 0; k < 8; k++) {
        s[k] += __shfl_xor(s[k], 8);
        s[k] += __shfl_xor(s[k], 16);
        s[k] += __shfl_xor(s[k], 32);
    }
    if (g == 0) {  // lanes 0..7: lane gl holds channels [8gl, 8gl+8)
        agg_consume(selfv, 1.f, s);  // + self row
        float d = dinv[wave];
        const float4* b4 = (const float4*)bias;
        float4 bb0 = b4[gl * 2], bb1 = b4[gl * 2 + 1];
        float o0 = fmaxf(fmaf(s[0], d, bb0.x), 0.f);
        float o1 = fmaxf(fmaf(s[1], d, bb0.y), 0.f);
        float o2 = fmaxf(fmaf(s[2], d, bb0.z), 0.f);
        float o3 = fmaxf(fmaf(s[3], d, bb0.w), 0.f);
        float o4 = fmaxf(fmaf(s[4], d, bb1.x), 0.f);
        float o5 = fmaxf(fmaf(s[5], d, bb1.y), 0.f);
        float o6 = fmaxf(fmaf(s[6], d, bb1.z), 0.f);
        float o7 = fmaxf(fmaf(s[7], d, bb1.w), 0.f);
        __half2 p0 = __floats2half2_rn(o0, o1);
        __half2 p1 = __floats2half2_rn(o2, o3);
        __half2 p2 = __floats2half2_rn(o4, o5);
        __half2 p3 = __floats2half2_rn(o6, o7);
        ((uint4*)acc)[(size_t)wave * 8 + gl] =
            make_uint4(*(unsigned int*)&p0, *(unsigned int*)&p1,
                       *(unsigned int*)&p2, *(unsigned int*)&p3);
    }
}

// ---------------------------------------------------------------------------
// gemm64: out[r,c] = f16( (in[r,:] @ W)[c] * dinv[r] ), f16 input, W pre-
// converted f16 col-major (8x b128 column load, no cvt). 64 rows/block
// (halves W re-reads and block count vs 32). A staged in LDS; uniform
// ds_read_b128 broadcast. 16 rows per wave.
// ---------------------------------------------------------------------------
__global__ __launch_bounds__(256) void gemm64(const unsigned short* __restrict__ in,
                                              const unsigned short* __restrict__ Wh,
                                              unsigned short* __restrict__ out,
                                              const float* __restrict__ dinv, int n) {
    __shared__ uint4 sA[64 * 8];  // 64 rows x 64 f16 = 8 KB
    int tid = threadIdx.x;
    int lane = tid & 63, wave = tid >> 6;
    unsigned int wu[32];
    {
        const uint4* col = (const uint4*)(Wh + (size_t)lane * 64);
#pragma unroll
        for (int j = 0; j < 8; j++) {
            uint4 w4 = col[j];
            wu[4 * j] = w4.x; wu[4 * j + 1] = w4.y;
            wu[4 * j + 2] = w4.z; wu[4 * j + 3] = w4.w;
        }
    }
    int base = blockIdx.x * 64;
    const uint2* A2 = (const uint2*)in;
    int lim = n * 16;
    for (int i = tid; i < 1024; i += 256) {
        int gi = base * 16 + i;
        ((uint2*)sA)[i] = (gi < lim) ? A2[gi] : make_uint2(0u, 0u);
    }
    __syncthreads();
    int r0 = base + wave * 16;
    int r1 = min(r0 + 16, n);
    for (int r = r0; r < r1; r++) {
        int rr = r - base;
        float a0 = 0.f, a1 = 0.f;
#pragma unroll
        for (int j = 0; j < 8; j++) {
            uint4 u = sA[rr * 8 + j];  // uniform addr -> LDS broadcast, b128
            a0 = dot2(u.x, wu[4 * j], a0);
            a1 = dot2(u.y, wu[4 * j + 1], a1);
            a0 = dot2(u.z, wu[4 * j + 2], a0);
            a1 = dot2(u.w, wu[4 * j + 3], a1);
        }
        __half hv = __float2half_rn((a0 + a1) * dinv[r]);
        out[(size_t)r * 64 + lane] = *(unsigned short*)&hv;
    }
}

// ---------------------------------------------------------------------------
// gemm32: out[r,0:32] = in[r,0:64] @ Wlin + blin (fp32 out). 64 rows/block.
// Lanes 32..63 compute duplicate columns, only lane<32 stores. Input (acc)
// is f16, already relu'd by aggregate.
// ---------------------------------------------------------------------------
__global__ __launch_bounds__(256) void gemm32(const unsigned short* __restrict__ in,
                                              const unsigned short* __restrict__ Wh,
                                              const float* __restrict__ b,
                                              float* __restrict__ out, int n) {
    __shared__ uint4 sA[64 * 8];
    int tid = threadIdx.x;
    int lane = tid & 63, wave = tid >> 6;
    int c = lane & 31;
    unsigned int wu[32];
    {
        const uint4* col = (const uint4*)(Wh + (size_t)c * 64);
#pragma unroll
        for (int j = 0; j < 8; j++) {
            uint4 w4 = col[j];
            wu[4 * j] = w4.x; wu[4 * j + 1] = w4.y;
            wu[4 * j + 2] = w4.z; wu[4 * j + 3] = w4.w;
        }
    }
    float bl = b[c];
    int base = blockIdx.x * 64;
    const uint2* A2 = (const uint2*)in;
    int lim = n * 16;
    for (int i = tid; i < 1024; i += 256) {
        int gi = base * 16 + i;
        ((uint2*)sA)[i] = (gi < lim) ? A2[gi] : make_uint2(0u, 0u);
    }
    __syncthreads();
    int r0 = base + wave * 16;
    int r1 = min(r0 + 16, n);
    for (int r = r0; r < r1; r++) {
        int rr = r - base;
        float a0 = 0.f, a1 = 0.f;
#pragma unroll
        for (int j = 0; j < 8; j++) {
            uint4 u = sA[rr * 8 + j];
            a0 = dot2(u.x, wu[4 * j], a0);
            a1 = dot2(u.y, wu[4 * j + 1], a1);
            a0 = dot2(u.z, wu[4 * j + 2], a0);
            a1 = dot2(u.w, wu[4 * j + 3], a1);
        }
        if (lane < 32) out[(size_t)r * 32 + c] = bl + a0 + a1;
    }
}

extern "C" void kernel_launch(void* const* d_in, const int* in_sizes, int n_in,
                              void* d_out, int out_size, void* d_ws, size_t ws_size,
                              hipStream_t stream) {
    (void)n_in; (void)out_size; (void)ws_size;
    const float* x    = (const float*)d_in[0];
    const void*  ei   = d_in[1];
    const float* W1   = (const float*)d_in[2];
    const float* b1   = (const float*)d_in[3];
    const float* W2   = (const float*)d_in[4];
    const float* b2   = (const float*)d_in[5];
    const float* Wlin = (const float*)d_in[6];
    const float* blin = (const float*)d_in[7];
    float* out = (float*)d_out;

    const int N = in_sizes[0] / IN_C;
    const int E = in_sizes[1] / 2;
    const int NB = (N + S_NODES - 1) / S_NODES;    // buckets (196)
    const int NEB = (E + CHUNK_E - 1) / CHUNK_E;   // bin blocks (391)
    const int GB = (N + 63) / 64;                  // 64-row gemm blocks (1563)

    char* ws = (char*)d_ws;
    size_t off = 0;
    auto alloc = [&](size_t bytes) -> void* {
        size_t a = (off + 255) & ~(size_t)255;
        off = a + bytes;
        return (void*)(ws + a);
    };
    int*   offs    = (int*)  alloc((size_t)(N + 1) * 4);
    float* dinv    = (float*)alloc((size_t)N * 4);
    int*   bcur    = (int*)  alloc((size_t)NB * 4);
    int*   rec     = (int*)  alloc((size_t)E * 4);
    int*   staging = (int*)  alloc((size_t)NB * S_CAP * 4);  // follows rec: OOB slack
    float* t32     = (float*)alloc((size_t)N * HID_C * 4);  // fp32 unscaled gemm1
    unsigned short* t16 = (unsigned short*)alloc((size_t)N * HID_C * 2);
    unsigned short* Wh2 = (unsigned short*)alloc(64 * 64 * 2);
    unsigned short* Whl = (unsigned short*)alloc(64 * 32 * 2);
    // acc aliases t32: t32's last read is place_fine; acc first written after.
    unsigned short* acc = (unsigned short*)t32;

    hipMemsetAsync(bcur, 0, (size_t)NB * 4, stream);

    // bin_edges (391 blocks) || gemm1 (1563 blocks) || W-convert (1 block)
    fat<<<NEB + GB + 1, 256, 0, stream>>>(ei, E, bcur, NB, staging, NEB, GB,
                                          x, W1, t32, N, W2, Wlin, Wh2, Whl);
    place_fine<<<NB, 1024, 0, stream>>>(staging, bcur, offs, dinv, rec,
                                        t32, t16, N, NB);

    aggregate<<<(N + 3) / 4, 256, 0, stream>>>(t16, offs, rec, dinv, b1, acc, N);
    gemm64<<<GB, 256, 0, stream>>>(acc, Wh2, t16, dinv, N);
    aggregate<<<(N + 3) / 4, 256, 0, stream>>>(t16, offs, rec, dinv, b2, acc, N);
    gemm32<<<GB, 256, 0, stream>>>(acc, Whl, blin, out, N);
}